// Round 9
// baseline (337.612 us; speedup 1.0000x reference)
//
#include <hip/hip_runtime.h>

#define FEAT 256
#define SEQ  2048
#define NBATCH 16

typedef float  f32x4  __attribute__((ext_vector_type(4)));
typedef __bf16 bf16x8 __attribute__((ext_vector_type(8)));

__device__ __forceinline__ unsigned short f2bf(float f) {
  union { float f; unsigned int u; } v; v.f = f;
  unsigned int r = (v.u + 0x7fffu + ((v.u >> 16) & 1u)) >> 16;
  return (unsigned short)r;
}
__device__ __forceinline__ float bf2f(unsigned short u) {
  union { unsigned int u; float f; } v; v.u = ((unsigned int)u) << 16;
  return v.f;
}
__device__ __forceinline__ unsigned int pack2bf(float a, float b) {
  return (unsigned int)f2bf(a) | ((unsigned int)f2bf(b) << 16);
}
// fast pack for the hot attention P path: round-half-up (5 inst vs 9 RNE).
__device__ __forceinline__ unsigned int pack2bf_ru(float a, float b) {
  union { float f; unsigned int u; } ua, ub;
  ua.f = a; ub.f = b;
  return ((ua.u + 0x8000u) >> 16) | ((ub.u + 0x8000u) & 0xffff0000u);
}

// async global->LDS DMA, 16B per lane. LDS image = lane-order byte copy of
// global; conflict-free layouts are baked into the GLOBAL layouts (k_wcvt for
// weights, k_posqkv for kb/vtb).
__device__ __forceinline__ void gld16(const unsigned short* g, unsigned short* l) {
  __builtin_amdgcn_global_load_lds(
      (const __attribute__((address_space(1))) unsigned int*)(const void*)g,
      (__attribute__((address_space(3))) unsigned int*)(void*)l, 16, 0, 0);
}

// copy one 16KB weight tile-pair (2 cts) global->LDS via DMA (256 threads)
__device__ __forceinline__ void dma_tile(const unsigned short* __restrict__ src,
                                         unsigned short* dst, int tid) {
#pragma unroll
  for (int q = 0; q < 4; ++q)
    gld16(src + q * 2048 + tid * 8, dst + q * 2048 + tid * 8);
}

// ---------------- kernel 0: convert weights fp32 -> bf16, CHUNK-TILED -------
// Layout (consumed by k_posqkv's DMA staging): for element W[f][k]:
//   ct=f>>4, col=f&15, chunk=k>>3 (==ks*4+quad), j=k&7
//   dst = ct*4096 + (chunk*16 + col)*8 + j
__global__ __launch_bounds__(256) void k_wcvt(
    const float* __restrict__ Wq, const float* __restrict__ Wk,
    const float* __restrict__ Wv, const float* __restrict__ W2,
    unsigned short* __restrict__ Wqb, unsigned short* __restrict__ Wkb,
    unsigned short* __restrict__ Wvb, unsigned short* __restrict__ W2b) {
  const int i = blockIdx.x * 256 + threadIdx.x;  // 65536 total
  const int f = i >> 8, kk = i & 255;
  const int dst = (f >> 4) * 4096 + ((kk >> 3) * 16 + (f & 15)) * 8 + (kk & 7);
  Wqb[dst] = f2bf(Wq[i]);
  Wkb[dst] = f2bf(Wk[i]);
  Wvb[dst] = f2bf(Wv[i]);
  W2b[dst] = f2bf(W2[i]);
}

// ------------- kernel 1: FUSED pos-encoder + h + q,k,v projections ---------
// DMA double-buffered weight staging. 32 tiles of 2 cts: 0..7 = W2 (phase B),
// 8..15 = Wk (->q), 16..23 = Wq (->k), 24..31 = Wv (->v). (Round-7 fixed the
// t<40 slip that recomputed the v projection twice.)
// Write-late stores (round-6). Reference name swap: q uses Wk/bk, k uses Wq/bq.
__global__ __launch_bounds__(256, 2) void k_posqkv(
    const float* __restrict__ x, const float* __restrict__ p,
    const float* __restrict__ W1, const float* __restrict__ b1,
    const unsigned short* __restrict__ W2b, const float* __restrict__ b2,
    const unsigned short* __restrict__ Wqb, const float* __restrict__ bq,
    const unsigned short* __restrict__ Wkb, const float* __restrict__ bk,
    const unsigned short* __restrict__ Wvb, const float* __restrict__ bv,
    unsigned short* __restrict__ qb, unsigned short* __restrict__ kb,
    unsigned short* __restrict__ vtb) {
  __shared__ __align__(16) unsigned short tlds[64 * 264];  // t, then h
  __shared__ __align__(16) unsigned short Wl[2][8192];     // 2 x 16KB tilepair
  __shared__ float pl[192];
  const int tid = threadIdx.x, blk = blockIdx.x;
  const int tok0 = blk * 64;
  if (tid < 192) pl[tid] = p[tok0 * 3 + tid];
  __syncthreads();
  // phase A: t = relu(p @ W1^T + b1); thread owns feature j = tid
  {
    const int j = tid;
    const float w0 = W1[j * 3 + 0], w1 = W1[j * 3 + 1], w2 = W1[j * 3 + 2];
    const float bb = b1[j];
#pragma unroll 4
    for (int tl = 0; tl < 64; ++tl) {
      float v = fmaf(pl[tl * 3 + 2], w2,
                fmaf(pl[tl * 3 + 1], w1, fmaf(pl[tl * 3 + 0], w0, bb)));
      v = v > 0.f ? v : 0.f;
      tlds[tl * 264 + j] = f2bf(v);
    }
  }
  __syncthreads();
  const int w = tid >> 6, lane = tid & 63;
  const int col = lane & 15, quad = lane >> 4;
  const int cp = w & 1;                 // ct-of-pair
  const int row0l = (w >> 1) * 32;      // local token base (M=32/wave)
  const int row0 = tok0 + row0l;        // global token base (32-aligned)

  // t-fragments, register-resident (frees tlds for in-place h overwrite)
  bf16x8 af0[8], af1[8];
  const unsigned short* a0r = tlds + (row0l + col) * 264 + quad * 8;
  const unsigned short* a1r = a0r + 16 * 264;
#pragma unroll
  for (int ks = 0; ks < 8; ++ks) {
    af0[ks] = *(const bf16x8*)(a0r + ks * 32);
    af1[ks] = *(const bf16x8*)(a1r + ks * 32);
  }
  // prologue: DMA tile 0 (W2 pair 0) -> buf 0; issue x loads for tile 0.
  dma_tile(W2b, Wl[0], tid);
  float xc[8], xn[8];
  {
    const int f0 = cp * 16 + col;
#pragma unroll
    for (int r = 0; r < 4; ++r) {
      xc[r]     = x[(size_t)(row0 + quad * 4 + r) * 256 + f0];
      xc[4 + r] = x[(size_t)(row0 + 16 + quad * 4 + r) * 256 + f0];
    }
  }
  // ---------------- phase B: 8 tiles, h = t @ W2^T + b2 + x -> tlds --------
#pragma unroll
  for (int tp = 0; tp < 8; ++tp) {
    __syncthreads();  // drains: tile-tp DMA, tile-tp x loads; orders buffers.
    {  // DMA next tile
      const int tn = tp + 1;
      const unsigned short* src = (tn < 8) ? (W2b + tn * 8192) : Wkb;
      dma_tile(src, Wl[tn & 1], tid);
    }
    if (tp < 7) {  // x prefetch for tile tp+1 (drained by next barrier)
      const int f0 = (2 * (tp + 1) + cp) * 16 + col;
#pragma unroll
      for (int r = 0; r < 4; ++r) {
        xn[r]     = x[(size_t)(row0 + quad * 4 + r) * 256 + f0];
        xn[4 + r] = x[(size_t)(row0 + 16 + quad * 4 + r) * 256 + f0];
      }
    }
    const int ct = 2 * tp + cp;
    f32x4 a0 = {0.f, 0.f, 0.f, 0.f}, a1 = {0.f, 0.f, 0.f, 0.f};
    const unsigned short* wbase = Wl[tp & 1] + cp * 4096 + (quad * 16 + col) * 8;
#pragma unroll
    for (int ks = 0; ks < 8; ++ks) {
      bf16x8 bfr = *(const bf16x8*)(wbase + ks * 512);
      a0 = __builtin_amdgcn_mfma_f32_16x16x32_bf16(af0[ks], bfr, a0, 0, 0, 0);
      a1 = __builtin_amdgcn_mfma_f32_16x16x32_bf16(af1[ks], bfr, a1, 0, 0, 0);
    }
    const int f = ct * 16 + col;
    const float bs = b2[f];
#pragma unroll
    for (int r = 0; r < 4; ++r) {
      tlds[(row0l + quad * 4 + r) * 264 + f]      = f2bf(a0[r] + bs + xc[r]);
      tlds[(row0l + 16 + quad * 4 + r) * 264 + f] = f2bf(a1[r] + bs + xc[4 + r]);
    }
#pragma unroll
    for (int r = 0; r < 8; ++r) xc[r] = xn[r];
  }
  // ------------- phase C: q,k,v (tiles 8..31), WRITE-LATE stores -----------
  int pmat = 0, pft = 0;        // pending-store state (uniform mat branch)
  unsigned short pvq[8];        // pending q/k values (static-indexed)
  uint4 pvv;                    // pending v value
#pragma unroll 1
  for (int t = 8; t < 32; ++t) {
    __syncthreads();  // drains tile-t DMA + prior stores; t==8 fences h-writes.
    // flush iter-(t-1) stores NOW: full-iteration window before the next
    // barrier's vmcnt(0) drain, instead of ~0 cycles.
    if (pmat == 1) {
      const int f = pft;
#pragma unroll
      for (int r = 0; r < 4; ++r) {
        qb[(size_t)(row0 + quad * 4 + r) * 256 + f] = pvq[r];
        qb[(size_t)(row0 + 16 + quad * 4 + r) * 256 + f] = pvq[4 + r];
      }
    } else if (pmat == 2) {
      const int f = pft;
      const int ks_ = f >> 5, qk = (f >> 3) & 3, jj = f & 7;
#pragma unroll
      for (int r = 0; r < 4; ++r) {
        const int tok = row0 + quad * 4 + r;
        const int b0 = tok >> 11, n = tok & 2047;
        const int g = n >> 5, key = n & 31;
        const size_t base =
            ((((size_t)(b0 * 64 + g) * 8 + ks_) * 4 + qk) * 32);
        kb[(base + key) * 8 + jj] = pvq[r];
        kb[(base + key + 16) * 8 + jj] = pvq[4 + r];
      }
    } else if (pmat == 3) {
      const int f = pft;
      const int t0 = row0 + quad * 4;
      const int b0 = t0 >> 11, n = t0 & 2047;
      const int g = n >> 5;  // n&31 == quad*4 -> qp == quad
      *(uint4*)(vtb + (((size_t)(b0 * 64 + g) * 4 + quad) * 256 + f) * 8) = pvv;
    }
    if (t < 31) {
      const int tn = t + 1;
      const int mt = tn >> 3, pr = tn & 7;
      const unsigned short* src = (mt == 1) ? Wkb : ((mt == 2) ? Wqb : Wvb);
      dma_tile(src + pr * 8192, Wl[tn & 1], tid);
    }
    if (t == 8) {  // reload A-frags: t replaced by h at same addresses
#pragma unroll
      for (int ks = 0; ks < 8; ++ks) {
        af0[ks] = *(const bf16x8*)(a0r + ks * 32);
        af1[ks] = *(const bf16x8*)(a1r + ks * 32);
      }
    }
    const int mat = t >> 3;             // 1=q(Wk), 2=k(Wq), 3=v(Wv)
    const int ct = 2 * (t & 7) + cp;
    f32x4 a0 = {0.f, 0.f, 0.f, 0.f}, a1 = {0.f, 0.f, 0.f, 0.f};
    const unsigned short* wbase = Wl[t & 1] + cp * 4096 + (quad * 16 + col) * 8;
#pragma unroll
    for (int ks = 0; ks < 8; ++ks) {
      bf16x8 bfr = *(const bf16x8*)(wbase + ks * 512);
      a0 = __builtin_amdgcn_mfma_f32_16x16x32_bf16(af0[ks], bfr, a0, 0, 0, 0);
      a1 = __builtin_amdgcn_mfma_f32_16x16x32_bf16(af1[ks], bfr, a1, 0, 0, 0);
    }
    const int f = ct * 16 + col;
    pmat = mat; pft = f;
    if (mat == 1) {  // q values (uses Wk/bk per reference swap)
      const float bs = bk[f];
#pragma unroll
      for (int r = 0; r < 4; ++r) {
        pvq[r]     = f2bf(a0[r] + bs);
        pvq[4 + r] = f2bf(a1[r] + bs);
      }
    } else if (mat == 2) {  // k values (Wq/bq)
      const float bs = bq[f];
#pragma unroll
      for (int r = 0; r < 4; ++r) {
        pvq[r]     = f2bf(a0[r] + bs);
        pvq[4 + r] = f2bf(a1[r] + bs);
      }
    } else {  // v values
      const float bs = bv[f];
      pvv.x = pack2bf(a0[0] + bs, a1[0] + bs);
      pvv.y = pack2bf(a0[1] + bs, a1[1] + bs);
      pvv.z = pack2bf(a0[2] + bs, a1[2] + bs);
      pvv.w = pack2bf(a0[3] + bs, a1[3] + bs);
    }
  }
  // final flush: t=31 was mat 3 (v), ct = 14+cp (last v ct-pair)
  {
    const int f = pft;
    const int t0 = row0 + quad * 4;
    const int b0 = t0 >> 11, n = t0 & 2047;
    const int g = n >> 5;
    *(uint4*)(vtb + (((size_t)(b0 * 64 + g) * 4 + quad) * 256 + f) * 8) = pvv;
  }
}

// ---------------- kernel 2: flash attention, reg-staged V (no V LDS) --------
// v9 (this round): V bypasses LDS entirely. Each lane's PV slice is a fixed
// 16x16B chunk of the V tile (quad*2048 + (ft*16+col)*8 == linear image of
// global vtb), so V(t-1) is loaded straight from global into 64 VGPRs (16 x
// dwordx4, coalesced 256B segments) at iter-t top and consumed by a pure-
// register PV cluster after QK(t) (~400cy of QK hides L2 latency; r5 showed
// merged-vs-separate clusters neutral). Deletes 16 of 32 ds_read_b128 per
// wave-iter (LDS pipe was 51% busy = top resource, r8 analysis) + the V DMA;
// LDS 64KB -> 32KB. Occupancy stays 2 blocks/CU; VGPR headroom is large
// (LDS-bound occupancy, m69 arithmetic). Per-element O accumulation sequence
// unchanged -> output bitwise identical to round 8.
// Swapped QK^T in-register P (r8, conflicts=0) retained.
// exp: __expf ONLY (native v_exp_f32; exp2f = OCML libcall regression).
__global__ __launch_bounds__(256, 2) void k_attn(
    const unsigned short* __restrict__ qb, const unsigned short* __restrict__ kb,
    const unsigned short* __restrict__ vtb, float* __restrict__ outA,
    unsigned short* __restrict__ obB, float* __restrict__ lbuf) {
  __shared__ __align__(16) unsigned short Kl[2][8192];   // [buf][ks][quad][key]
  const int tid = threadIdx.x;
  const int bx = blockIdx.x, b = blockIdx.y, h = blockIdx.z;
  const int w = tid >> 6, lane = tid & 63;
  const int col = lane & 15, quad = lane >> 4;
  const int n0 = bx * 128 + w * 32;
  const float scale = 0.0625f;  // 1/sqrt(256)

  bf16x8 qf0[8], qf1[8];
  const unsigned short* qrow0 = qb + (size_t)(b * 2048 + n0 + col) * 256 + quad * 8;
  const unsigned short* qrow1 = qrow0 + 16 * 256;
#pragma unroll
  for (int ks = 0; ks < 8; ++ks) {
    qf0[ks] = *(const bf16x8*)(qrow0 + ks * 32);
    qf1[ks] = *(const bf16x8*)(qrow1 + ks * 32);
  }

  f32x4 O0[16], O1[16];
#pragma unroll
  for (int ft = 0; ft < 16; ++ft) {
    O0[ft] = (f32x4){0.f, 0.f, 0.f, 0.f};
    O1[ft] = (f32x4){0.f, 0.f, 0.f, 0.f};
  }
  float ls0 = 0.f, ls1 = 0.f;  // per-lane l partial (query = lane&15)

  const unsigned short* kbase = kb + (size_t)b * 64 * 8192;
  // per-lane global V base: lane's fixed slice of each tile
  const unsigned short* vlane =
      vtb + (size_t)b * 64 * 8192 + quad * 2048 + col * 8;
  const int kt0 = h * 32;
  const int sl = w * 2048 + lane * 8;  // wave slice base (shorts)

  f32x4 s00, s01, s10, s11;  // s[q-block][k-block], swapped: row=key, col=query
  bf16x8 pf0, pf1;           // P fragments carried across iterations
  bf16x8 vr[16];             // V(t-1) register tile (lane slice, 64 VGPR)

  auto LOADV = [&](int t) {  // issue 16 global dwordx4 for tile t's lane slice
    const unsigned short* vg = vlane + (size_t)(kt0 + t) * 8192;
#pragma unroll
    for (int ft = 0; ft < 16; ++ft) vr[ft] = *(const bf16x8*)(vg + ft * 128);
  };
  auto QK = [&](const unsigned short* Kc) {
    s00 = (f32x4){0.f, 0.f, 0.f, 0.f}; s01 = (f32x4){0.f, 0.f, 0.f, 0.f};
    s10 = (f32x4){0.f, 0.f, 0.f, 0.f}; s11 = (f32x4){0.f, 0.f, 0.f, 0.f};
    __builtin_amdgcn_s_setprio(1);
#pragma unroll
    for (int ks = 0; ks < 8; ++ks) {
      const unsigned short* kc = Kc + (ks * 4 + quad) * 256 + col * 8;
      bf16x8 k0 = *(const bf16x8*)(kc);
      bf16x8 k1 = *(const bf16x8*)(kc + 128);
      s00 = __builtin_amdgcn_mfma_f32_16x16x32_bf16(k0, qf0[ks], s00, 0, 0, 0);
      s01 = __builtin_amdgcn_mfma_f32_16x16x32_bf16(k1, qf0[ks], s01, 0, 0, 0);
      s10 = __builtin_amdgcn_mfma_f32_16x16x32_bf16(k0, qf1[ks], s10, 0, 0, 0);
      s11 = __builtin_amdgcn_mfma_f32_16x16x32_bf16(k1, qf1[ks], s11, 0, 0, 0);
    }
    __builtin_amdgcn_s_setprio(0);
  };
  auto PVr = [&]() {  // pure-register PV: pf x vr -> O (no LDS)
    __builtin_amdgcn_s_setprio(1);
#pragma unroll
    for (int ft = 0; ft < 16; ++ft) {
      O0[ft] = __builtin_amdgcn_mfma_f32_16x16x32_bf16(pf0, vr[ft], O0[ft], 0, 0, 0);
      O1[ft] = __builtin_amdgcn_mfma_f32_16x16x32_bf16(pf1, vr[ft], O1[ft], 0, 0, 0);
    }
    __builtin_amdgcn_s_setprio(0);
  };
  auto EXPP = [&]() {
    // exp in registers; pf built by packing (k-block0[r], k-block1[r]) pairs
    // -> key order [q4+0, 16+q4+0, q4+1, ...] == vtb's baked interleave.
    float p0[8], p1[8];
#pragma unroll
    for (int r = 0; r < 4; ++r) {
      p0[r]     = __expf(fmaf(s00[r], scale, -8.0f));
      p0[4 + r] = __expf(fmaf(s01[r], scale, -8.0f));
      p1[r]     = __expf(fmaf(s10[r], scale, -8.0f));
      p1[4 + r] = __expf(fmaf(s11[r], scale, -8.0f));
    }
#pragma unroll
    for (int r = 0; r < 8; ++r) { ls0 += p0[r]; ls1 += p1[r]; }
    union { uint4 u; bf16x8 v; } c0, c1;
    c0.u.x = pack2bf_ru(p0[0], p0[4]);
    c0.u.y = pack2bf_ru(p0[1], p0[5]);
    c0.u.z = pack2bf_ru(p0[2], p0[6]);
    c0.u.w = pack2bf_ru(p0[3], p0[7]);
    c1.u.x = pack2bf_ru(p1[0], p1[4]);
    c1.u.y = pack2bf_ru(p1[1], p1[5]);
    c1.u.z = pack2bf_ru(p1[2], p1[6]);
    c1.u.w = pack2bf_ru(p1[3], p1[7]);
    pf0 = c0.v;
    pf1 = c1.v;
  };

  // prologue: DMA K(0) -> Kl[0]
#pragma unroll
  for (int q = 0; q < 4; ++q)
    gld16(kbase + (size_t)kt0 * 8192 + sl + q * 512, &Kl[0][sl + q * 512]);

  // ---- iter 0 (peel: no PV yet) ----
  __syncthreads();  // drains K(0)
#pragma unroll
  for (int q = 0; q < 4; ++q)
    gld16(kbase + (size_t)(kt0 + 1) * 8192 + sl + q * 512, &Kl[1][sl + q * 512]);
  QK(Kl[0]);
  EXPP();  // -> pf(0)

  // ---- main loop t = 1..31: QK(t) ; PV(t-1) [reg V] ; exp(t) ----
#pragma unroll 1
  for (int t = 1; t < 32; ++t) {
    __syncthreads();  // ONLY barrier: drains K(t) DMA, orders K buffers
    if (t < 31) {     // DMA K(t+1) -> Kl[(t+1)&1] (last read by QK(t-1))
      const size_t kbo = (size_t)(kt0 + t + 1) * 8192;
#pragma unroll
      for (int q = 0; q < 4; ++q)
        gld16(kbase + kbo + sl + q * 512, &Kl[(t + 1) & 1][sl + q * 512]);
    }
    LOADV(t - 1);      // V(t-1) -> regs; vmcnt wait lands after QK (hidden)
    QK(Kl[t & 1]);     // LDS K reads + MFMA cluster
    PVr();             // pure-register MFMA cluster (uses carried pf(t-1))
    EXPP();            // VALU tail; -> pf(t)
  }
  // final PV(31): load V(31) slice, then pure-reg PV. No barrier needed.
  LOADV(31);
  PVr();

  // epilogue: write UNDIVIDED partial O and partial l (FULLY UNROLLED).
  // l: per-lane partial covers keys {quad*4+r} ∪ {16+quad*4+r}; reduce
  // across the 4 quads (lanes sharing lane&15) via xor 16, 32.
  float l0 = ls0 + __shfl_xor(ls0, 16);
  l0 += __shfl_xor(l0, 32);
  float l1 = ls1 + __shfl_xor(ls1, 16);
  l1 += __shfl_xor(l1, 32);
  const int lb = (h == 0 ? 0 : 32768) + b * 2048 + n0;
  if (quad == 0) {  // one lane per query
    lbuf[lb + col] = l0;
    lbuf[lb + 16 + col] = l1;
  }
  if (h == 0) {
#pragma unroll
    for (int ft = 0; ft < 16; ++ft) {
#pragma unroll
      for (int r = 0; r < 4; ++r) {
        const int n = n0 + quad * 4 + r;
        outA[(size_t)(b * 2048 + n) * 256 + ft * 16 + col] = O0[ft][r];
        outA[(size_t)(b * 2048 + n + 16) * 256 + ft * 16 + col] = O1[ft][r];
      }
    }
  } else {
#pragma unroll
    for (int ft = 0; ft < 16; ++ft) {
#pragma unroll
      for (int r = 0; r < 4; ++r) {
        const int n = n0 + quad * 4 + r;
        obB[(size_t)(b * 2048 + n) * 256 + ft * 16 + col] = f2bf(O0[ft][r]);
        obB[(size_t)(b * 2048 + n + 16) * 256 + ft * 16 + col] = f2bf(O1[ft][r]);
      }
    }
  }
}

// ---------------- kernel 3: combine K-split partials ----------------
__global__ __launch_bounds__(256) void k_reduce(
    float* __restrict__ out, const unsigned short* __restrict__ ob,
    const float* __restrict__ lbuf) {
  const size_t i4 = (size_t)blockIdx.x * 256 + threadIdx.x;  // 2M float4's
  const int bn = (int)(i4 >> 6);
  const float rl = 1.0f / (lbuf[bn] + lbuf[32768 + bn]);
  float4 o = ((const float4*)out)[i4];
  ushort4 b4 = ((const ushort4*)ob)[i4];
  o.x = (o.x + bf2f(b4.x)) * rl;
  o.y = (o.y + bf2f(b4.y)) * rl;
  o.z = (o.z + bf2f(b4.z)) * rl;
  o.w = (o.w + bf2f(b4.w)) * rl;
  ((float4*)out)[i4] = o;
}

// ---------------- launcher ----------------
extern "C" void kernel_launch(void* const* d_in, const int* in_sizes, int n_in,
                              void* d_out, int out_size, void* d_ws, size_t ws_size,
                              hipStream_t stream) {
  const float* x  = (const float*)d_in[0];
  const float* p  = (const float*)d_in[1];
  const float* Wq = (const float*)d_in[2];
  const float* bq = (const float*)d_in[3];
  const float* Wk = (const float*)d_in[4];
  const float* bk = (const float*)d_in[5];
  const float* Wv = (const float*)d_in[6];
  const float* bv = (const float*)d_in[7];
  const float* W1 = (const float*)d_in[8];
  const float* b1 = (const float*)d_in[9];
  const float* W2 = (const float*)d_in[10];
  const float* b2 = (const float*)d_in[11];
  float* out = (float*)d_out;

  char* ws = (char*)d_ws;
  unsigned short* W2b = (unsigned short*)(ws + 0);
  unsigned short* Wqb = (unsigned short*)(ws + 131072);
  unsigned short* Wkb = (unsigned short*)(ws + 262144);
  unsigned short* Wvb = (unsigned short*)(ws + 393216);
  unsigned short* obB = (unsigned short*)(ws + 524288);            // 16 MB
  unsigned short* qb  = (unsigned short*)(ws + 524288 + 16777216);
  unsigned short* kb  = (unsigned short*)(ws + 524288 + 2 * 16777216);
  unsigned short* vtb = (unsigned short*)(ws + 524288 + 3 * 16777216);
  float* lbuf = (float*)(ws + 524288 + 4 * 16777216);              // 256 KB
  // total ws use: 524288 + 4*16777216 + 262144 = 67,895,296 bytes

  k_wcvt<<<256, 256, 0, stream>>>(Wq, Wk, Wv, W2, Wqb, Wkb, Wvb, W2b);
  k_posqkv<<<512, 256, 0, stream>>>(x, p, W1, b1, W2b, b2,
                                    Wqb, bq, Wkb, bk, Wvb, bv, qb, kb, vtb);
  k_attn<<<dim3(16, 16, 2), 256, 0, stream>>>(qb, kb, vtb, out, obB, lbuf);
  k_reduce<<<8192, 256, 0, stream>>>(out, obB, lbuf);
}

// Round 10
// 212.619 us; speedup vs baseline: 1.5879x; 1.5879x over previous
//
#include <hip/hip_runtime.h>

#define FEAT 256
#define SEQ  2048
#define NBATCH 16

typedef float  f32x4  __attribute__((ext_vector_type(4)));
typedef __bf16 bf16x8 __attribute__((ext_vector_type(8)));

__device__ __forceinline__ unsigned short f2bf(float f) {
  union { float f; unsigned int u; } v; v.f = f;
  unsigned int r = (v.u + 0x7fffu + ((v.u >> 16) & 1u)) >> 16;
  return (unsigned short)r;
}
__device__ __forceinline__ float bf2f(unsigned short u) {
  union { unsigned int u; float f; } v; v.u = ((unsigned int)u) << 16;
  return v.f;
}
__device__ __forceinline__ unsigned int pack2bf(float a, float b) {
  return (unsigned int)f2bf(a) | ((unsigned int)f2bf(b) << 16);
}
// fast pack for the hot attention P path: round-half-up (5 inst vs 9 RNE).
__device__ __forceinline__ unsigned int pack2bf_ru(float a, float b) {
  union { float f; unsigned int u; } ua, ub;
  ua.f = a; ub.f = b;
  return ((ua.u + 0x8000u) >> 16) | ((ub.u + 0x8000u) & 0xffff0000u);
}

// async global->LDS DMA, 16B per lane. LDS image = lane-order byte copy of
// global; conflict-free layouts are baked into the GLOBAL layouts (k_wcvt for
// weights, k_posqkv for kb/vtb).
__device__ __forceinline__ void gld16(const unsigned short* g, unsigned short* l) {
  __builtin_amdgcn_global_load_lds(
      (const __attribute__((address_space(1))) unsigned int*)(const void*)g,
      (__attribute__((address_space(3))) unsigned int*)(void*)l, 16, 0, 0);
}

// copy one 16KB weight tile-pair (2 cts) global->LDS via DMA (256 threads)
__device__ __forceinline__ void dma_tile(const unsigned short* __restrict__ src,
                                         unsigned short* dst, int tid) {
#pragma unroll
  for (int q = 0; q < 4; ++q)
    gld16(src + q * 2048 + tid * 8, dst + q * 2048 + tid * 8);
}

// ---------------- kernel 0: convert weights fp32 -> bf16, CHUNK-TILED -------
// Layout (consumed by k_posqkv's DMA staging): for element W[f][k]:
//   ct=f>>4, col=f&15, chunk=k>>3 (==ks*4+quad), j=k&7
//   dst = ct*4096 + (chunk*16 + col)*8 + j
__global__ __launch_bounds__(256) void k_wcvt(
    const float* __restrict__ Wq, const float* __restrict__ Wk,
    const float* __restrict__ Wv, const float* __restrict__ W2,
    unsigned short* __restrict__ Wqb, unsigned short* __restrict__ Wkb,
    unsigned short* __restrict__ Wvb, unsigned short* __restrict__ W2b) {
  const int i = blockIdx.x * 256 + threadIdx.x;  // 65536 total
  const int f = i >> 8, kk = i & 255;
  const int dst = (f >> 4) * 4096 + ((kk >> 3) * 16 + (f & 15)) * 8 + (kk & 7);
  Wqb[dst] = f2bf(Wq[i]);
  Wkb[dst] = f2bf(Wk[i]);
  Wvb[dst] = f2bf(Wv[i]);
  W2b[dst] = f2bf(W2[i]);
}

// ------------- kernel 1: FUSED pos-encoder + h + q,k,v projections ---------
// DMA double-buffered weight staging. 32 tiles of 2 cts: 0..7 = W2 (phase B),
// 8..15 = Wk (->q), 16..23 = Wq (->k), 24..31 = Wv (->v). (Round-7 fixed the
// t<40 slip that recomputed the v projection twice.)
// Write-late stores (round-6). Reference name swap: q uses Wk/bk, k uses Wq/bq.
__global__ __launch_bounds__(256, 2) void k_posqkv(
    const float* __restrict__ x, const float* __restrict__ p,
    const float* __restrict__ W1, const float* __restrict__ b1,
    const unsigned short* __restrict__ W2b, const float* __restrict__ b2,
    const unsigned short* __restrict__ Wqb, const float* __restrict__ bq,
    const unsigned short* __restrict__ Wkb, const float* __restrict__ bk,
    const unsigned short* __restrict__ Wvb, const float* __restrict__ bv,
    unsigned short* __restrict__ qb, unsigned short* __restrict__ kb,
    unsigned short* __restrict__ vtb) {
  __shared__ __align__(16) unsigned short tlds[64 * 264];  // t, then h
  __shared__ __align__(16) unsigned short Wl[2][8192];     // 2 x 16KB tilepair
  __shared__ float pl[192];
  const int tid = threadIdx.x, blk = blockIdx.x;
  const int tok0 = blk * 64;
  if (tid < 192) pl[tid] = p[tok0 * 3 + tid];
  __syncthreads();
  // phase A: t = relu(p @ W1^T + b1); thread owns feature j = tid
  {
    const int j = tid;
    const float w0 = W1[j * 3 + 0], w1 = W1[j * 3 + 1], w2 = W1[j * 3 + 2];
    const float bb = b1[j];
#pragma unroll 4
    for (int tl = 0; tl < 64; ++tl) {
      float v = fmaf(pl[tl * 3 + 2], w2,
                fmaf(pl[tl * 3 + 1], w1, fmaf(pl[tl * 3 + 0], w0, bb)));
      v = v > 0.f ? v : 0.f;
      tlds[tl * 264 + j] = f2bf(v);
    }
  }
  __syncthreads();
  const int w = tid >> 6, lane = tid & 63;
  const int col = lane & 15, quad = lane >> 4;
  const int cp = w & 1;                 // ct-of-pair
  const int row0l = (w >> 1) * 32;      // local token base (M=32/wave)
  const int row0 = tok0 + row0l;        // global token base (32-aligned)

  // t-fragments, register-resident (frees tlds for in-place h overwrite)
  bf16x8 af0[8], af1[8];
  const unsigned short* a0r = tlds + (row0l + col) * 264 + quad * 8;
  const unsigned short* a1r = a0r + 16 * 264;
#pragma unroll
  for (int ks = 0; ks < 8; ++ks) {
    af0[ks] = *(const bf16x8*)(a0r + ks * 32);
    af1[ks] = *(const bf16x8*)(a1r + ks * 32);
  }
  // prologue: DMA tile 0 (W2 pair 0) -> buf 0; issue x loads for tile 0.
  dma_tile(W2b, Wl[0], tid);
  float xc[8], xn[8];
  {
    const int f0 = cp * 16 + col;
#pragma unroll
    for (int r = 0; r < 4; ++r) {
      xc[r]     = x[(size_t)(row0 + quad * 4 + r) * 256 + f0];
      xc[4 + r] = x[(size_t)(row0 + 16 + quad * 4 + r) * 256 + f0];
    }
  }
  // ---------------- phase B: 8 tiles, h = t @ W2^T + b2 + x -> tlds --------
#pragma unroll
  for (int tp = 0; tp < 8; ++tp) {
    __syncthreads();  // drains: tile-tp DMA, tile-tp x loads; orders buffers.
    {  // DMA next tile
      const int tn = tp + 1;
      const unsigned short* src = (tn < 8) ? (W2b + tn * 8192) : Wkb;
      dma_tile(src, Wl[tn & 1], tid);
    }
    if (tp < 7) {  // x prefetch for tile tp+1 (drained by next barrier)
      const int f0 = (2 * (tp + 1) + cp) * 16 + col;
#pragma unroll
      for (int r = 0; r < 4; ++r) {
        xn[r]     = x[(size_t)(row0 + quad * 4 + r) * 256 + f0];
        xn[4 + r] = x[(size_t)(row0 + 16 + quad * 4 + r) * 256 + f0];
      }
    }
    const int ct = 2 * tp + cp;
    f32x4 a0 = {0.f, 0.f, 0.f, 0.f}, a1 = {0.f, 0.f, 0.f, 0.f};
    const unsigned short* wbase = Wl[tp & 1] + cp * 4096 + (quad * 16 + col) * 8;
#pragma unroll
    for (int ks = 0; ks < 8; ++ks) {
      bf16x8 bfr = *(const bf16x8*)(wbase + ks * 512);
      a0 = __builtin_amdgcn_mfma_f32_16x16x32_bf16(af0[ks], bfr, a0, 0, 0, 0);
      a1 = __builtin_amdgcn_mfma_f32_16x16x32_bf16(af1[ks], bfr, a1, 0, 0, 0);
    }
    const int f = ct * 16 + col;
    const float bs = b2[f];
#pragma unroll
    for (int r = 0; r < 4; ++r) {
      tlds[(row0l + quad * 4 + r) * 264 + f]      = f2bf(a0[r] + bs + xc[r]);
      tlds[(row0l + 16 + quad * 4 + r) * 264 + f] = f2bf(a1[r] + bs + xc[4 + r]);
    }
#pragma unroll
    for (int r = 0; r < 8; ++r) xc[r] = xn[r];
  }
  // ------------- phase C: q,k,v (tiles 8..31), WRITE-LATE stores -----------
  int pmat = 0, pft = 0;        // pending-store state (uniform mat branch)
  unsigned short pvq[8];        // pending q/k values (static-indexed)
  uint4 pvv;                    // pending v value
#pragma unroll 1
  for (int t = 8; t < 32; ++t) {
    __syncthreads();  // drains tile-t DMA + prior stores; t==8 fences h-writes.
    // flush iter-(t-1) stores NOW: full-iteration window before the next
    // barrier's vmcnt(0) drain, instead of ~0 cycles.
    if (pmat == 1) {
      const int f = pft;
#pragma unroll
      for (int r = 0; r < 4; ++r) {
        qb[(size_t)(row0 + quad * 4 + r) * 256 + f] = pvq[r];
        qb[(size_t)(row0 + 16 + quad * 4 + r) * 256 + f] = pvq[4 + r];
      }
    } else if (pmat == 2) {
      const int f = pft;
      const int ks_ = f >> 5, qk = (f >> 3) & 3, jj = f & 7;
#pragma unroll
      for (int r = 0; r < 4; ++r) {
        const int tok = row0 + quad * 4 + r;
        const int b0 = tok >> 11, n = tok & 2047;
        const int g = n >> 5, key = n & 31;
        const size_t base =
            ((((size_t)(b0 * 64 + g) * 8 + ks_) * 4 + qk) * 32);
        kb[(base + key) * 8 + jj] = pvq[r];
        kb[(base + key + 16) * 8 + jj] = pvq[4 + r];
      }
    } else if (pmat == 3) {
      const int f = pft;
      const int t0 = row0 + quad * 4;
      const int b0 = t0 >> 11, n = t0 & 2047;
      const int g = n >> 5;  // n&31 == quad*4 -> qp == quad
      *(uint4*)(vtb + (((size_t)(b0 * 64 + g) * 4 + quad) * 256 + f) * 8) = pvv;
    }
    if (t < 31) {
      const int tn = t + 1;
      const int mt = tn >> 3, pr = tn & 7;
      const unsigned short* src = (mt == 1) ? Wkb : ((mt == 2) ? Wqb : Wvb);
      dma_tile(src + pr * 8192, Wl[tn & 1], tid);
    }
    if (t == 8) {  // reload A-frags: t replaced by h at same addresses
#pragma unroll
      for (int ks = 0; ks < 8; ++ks) {
        af0[ks] = *(const bf16x8*)(a0r + ks * 32);
        af1[ks] = *(const bf16x8*)(a1r + ks * 32);
      }
    }
    const int mat = t >> 3;             // 1=q(Wk), 2=k(Wq), 3=v(Wv)
    const int ct = 2 * (t & 7) + cp;
    f32x4 a0 = {0.f, 0.f, 0.f, 0.f}, a1 = {0.f, 0.f, 0.f, 0.f};
    const unsigned short* wbase = Wl[t & 1] + cp * 4096 + (quad * 16 + col) * 8;
#pragma unroll
    for (int ks = 0; ks < 8; ++ks) {
      bf16x8 bfr = *(const bf16x8*)(wbase + ks * 512);
      a0 = __builtin_amdgcn_mfma_f32_16x16x32_bf16(af0[ks], bfr, a0, 0, 0, 0);
      a1 = __builtin_amdgcn_mfma_f32_16x16x32_bf16(af1[ks], bfr, a1, 0, 0, 0);
    }
    const int f = ct * 16 + col;
    pmat = mat; pft = f;
    if (mat == 1) {  // q values (uses Wk/bk per reference swap)
      const float bs = bk[f];
#pragma unroll
      for (int r = 0; r < 4; ++r) {
        pvq[r]     = f2bf(a0[r] + bs);
        pvq[4 + r] = f2bf(a1[r] + bs);
      }
    } else if (mat == 2) {  // k values (Wq/bq)
      const float bs = bq[f];
#pragma unroll
      for (int r = 0; r < 4; ++r) {
        pvq[r]     = f2bf(a0[r] + bs);
        pvq[4 + r] = f2bf(a1[r] + bs);
      }
    } else {  // v values
      const float bs = bv[f];
      pvv.x = pack2bf(a0[0] + bs, a1[0] + bs);
      pvv.y = pack2bf(a0[1] + bs, a1[1] + bs);
      pvv.z = pack2bf(a0[2] + bs, a1[2] + bs);
      pvv.w = pack2bf(a0[3] + bs, a1[3] + bs);
    }
  }
  // final flush: t=31 was mat 3 (v), ct = 14+cp (last v ct-pair)
  {
    const int f = pft;
    const int t0 = row0 + quad * 4;
    const int b0 = t0 >> 11, n = t0 & 2047;
    const int g = n >> 5;
    *(uint4*)(vtb + (((size_t)(b0 * 64 + g) * 4 + quad) * 256 + f) * 8) = pvv;
  }
}

// ---------------- kernel 2: flash attention, r8 structure + XCD swizzle -----
// v10: REVERT round-9's reg-staged V (FETCH 142->383MB, L2 thrash across
// XCDs, MfmaUtil 36->14, 79.8->200us) back to the round-8-verified kernel
// (79.8us, conflicts=0): K,V double-buffered in LDS via DMA, ONE barrier/iter,
// swapped QK^T with in-register P, merged {QK(t) ∥ PV(t-1)}.
// NEW: b-clustered XCD swizzle (T1). Grid flattened to 512 1-D blocks;
// hardware round-robin XCD = linear%8 (512%8==0, bijective). Decode puts
// batches {2x,2x+1} on XCD x: all 64 blocks of an XCD (= its 32 CUs x 2
// resident blocks) share 2 batches -> per-XCD K/V working set = 4MB = one
// L2. r8's FETCH (142MB ~ 3x unique bytes) was cross-XCD duplicate fetches.
// Pure work permutation -> output identical; if the %8 placement assumption
// is wrong this is neutral (perf heuristic only, G16).
// exp: __expf ONLY (native v_exp_f32; exp2f = OCML libcall regression).
__global__ __launch_bounds__(256, 2) void k_attn(
    const unsigned short* __restrict__ qb, const unsigned short* __restrict__ kb,
    const unsigned short* __restrict__ vtb, float* __restrict__ outA,
    unsigned short* __restrict__ obB, float* __restrict__ lbuf) {
  __shared__ __align__(16) unsigned short Kl[2][8192];   // [buf][ks][quad][key]
  __shared__ __align__(16) unsigned short Vt[2][8192];   // [buf][qp][f]
  const int tid = threadIdx.x;
  // XCD-aware decode: xcd = L%8 hosts batches {2*xcd, 2*xcd+1}
  const int L = blockIdx.x;              // [0,512)
  const int xcd = L & 7, idx = L >> 3;   // idx in [0,64)
  const int b = xcd * 2 + (idx & 1);
  const int rem = idx >> 1;              // [0,32)
  const int bx = rem & 15, h = rem >> 4;
  const int w = tid >> 6, lane = tid & 63;
  const int col = lane & 15, quad = lane >> 4;
  const int n0 = bx * 128 + w * 32;
  const float scale = 0.0625f;  // 1/sqrt(256)

  bf16x8 qf0[8], qf1[8];
  const unsigned short* qrow0 = qb + (size_t)(b * 2048 + n0 + col) * 256 + quad * 8;
  const unsigned short* qrow1 = qrow0 + 16 * 256;
#pragma unroll
  for (int ks = 0; ks < 8; ++ks) {
    qf0[ks] = *(const bf16x8*)(qrow0 + ks * 32);
    qf1[ks] = *(const bf16x8*)(qrow1 + ks * 32);
  }

  f32x4 O0[16], O1[16];
#pragma unroll
  for (int ft = 0; ft < 16; ++ft) {
    O0[ft] = (f32x4){0.f, 0.f, 0.f, 0.f};
    O1[ft] = (f32x4){0.f, 0.f, 0.f, 0.f};
  }
  float ls0 = 0.f, ls1 = 0.f;  // per-lane l partial (query = lane&15)

  const unsigned short* kbase = kb + (size_t)b * 64 * 8192;
  const unsigned short* vbase = vtb + (size_t)b * 64 * 8192;
  const int kt0 = h * 32;
  const int sl = w * 2048 + lane * 8;  // wave slice base (shorts)

  f32x4 s00, s01, s10, s11;  // s[q-block][k-block], swapped: row=key, col=query
  bf16x8 pf0, pf1;           // P fragments carried across iterations

  // merged: QK(t) interleaved with PV(t-1). PV MFMAs (pf/V) are independent
  // of the K ds_reads -> they fill the lgkm-wait holes in QK's chain.
  auto QKPV = [&](const unsigned short* Kc, const unsigned short* Vc) {
    s00 = (f32x4){0.f, 0.f, 0.f, 0.f}; s01 = (f32x4){0.f, 0.f, 0.f, 0.f};
    s10 = (f32x4){0.f, 0.f, 0.f, 0.f}; s11 = (f32x4){0.f, 0.f, 0.f, 0.f};
    __builtin_amdgcn_s_setprio(1);
#pragma unroll
    for (int ks = 0; ks < 8; ++ks) {
      const unsigned short* kc = Kc + (ks * 4 + quad) * 256 + col * 8;
      bf16x8 k0 = *(const bf16x8*)(kc);
      bf16x8 k1 = *(const bf16x8*)(kc + 128);
      const unsigned short* vc = Vc + quad * 2048 + (2 * ks * 16 + col) * 8;
      bf16x8 vf0 = *(const bf16x8*)(vc);
      bf16x8 vf1 = *(const bf16x8*)(vc + 128);
      s00 = __builtin_amdgcn_mfma_f32_16x16x32_bf16(k0, qf0[ks], s00, 0, 0, 0);
      O0[2 * ks] = __builtin_amdgcn_mfma_f32_16x16x32_bf16(pf0, vf0, O0[2 * ks], 0, 0, 0);
      s10 = __builtin_amdgcn_mfma_f32_16x16x32_bf16(k0, qf1[ks], s10, 0, 0, 0);
      O1[2 * ks] = __builtin_amdgcn_mfma_f32_16x16x32_bf16(pf1, vf0, O1[2 * ks], 0, 0, 0);
      s01 = __builtin_amdgcn_mfma_f32_16x16x32_bf16(k1, qf0[ks], s01, 0, 0, 0);
      O0[2 * ks + 1] = __builtin_amdgcn_mfma_f32_16x16x32_bf16(pf0, vf1, O0[2 * ks + 1], 0, 0, 0);
      s11 = __builtin_amdgcn_mfma_f32_16x16x32_bf16(k1, qf1[ks], s11, 0, 0, 0);
      O1[2 * ks + 1] = __builtin_amdgcn_mfma_f32_16x16x32_bf16(pf1, vf1, O1[2 * ks + 1], 0, 0, 0);
    }
    __builtin_amdgcn_s_setprio(0);
  };
  auto QK = [&](const unsigned short* Kc) {  // iter-0 peel (no PV yet)
    s00 = (f32x4){0.f, 0.f, 0.f, 0.f}; s01 = (f32x4){0.f, 0.f, 0.f, 0.f};
    s10 = (f32x4){0.f, 0.f, 0.f, 0.f}; s11 = (f32x4){0.f, 0.f, 0.f, 0.f};
    __builtin_amdgcn_s_setprio(1);
#pragma unroll
    for (int ks = 0; ks < 8; ++ks) {
      const unsigned short* kc = Kc + (ks * 4 + quad) * 256 + col * 8;
      bf16x8 k0 = *(const bf16x8*)(kc);
      bf16x8 k1 = *(const bf16x8*)(kc + 128);
      s00 = __builtin_amdgcn_mfma_f32_16x16x32_bf16(k0, qf0[ks], s00, 0, 0, 0);
      s01 = __builtin_amdgcn_mfma_f32_16x16x32_bf16(k1, qf0[ks], s01, 0, 0, 0);
      s10 = __builtin_amdgcn_mfma_f32_16x16x32_bf16(k0, qf1[ks], s10, 0, 0, 0);
      s11 = __builtin_amdgcn_mfma_f32_16x16x32_bf16(k1, qf1[ks], s11, 0, 0, 0);
    }
    __builtin_amdgcn_s_setprio(0);
  };
  auto PV = [&](const unsigned short* Vc) {  // final-tile peel
    __builtin_amdgcn_s_setprio(1);
#pragma unroll
    for (int ft = 0; ft < 16; ++ft) {
      bf16x8 vf = *(const bf16x8*)(Vc + quad * 2048 + (ft * 16 + col) * 8);
      O0[ft] = __builtin_amdgcn_mfma_f32_16x16x32_bf16(pf0, vf, O0[ft], 0, 0, 0);
      O1[ft] = __builtin_amdgcn_mfma_f32_16x16x32_bf16(pf1, vf, O1[ft], 0, 0, 0);
    }
    __builtin_amdgcn_s_setprio(0);
  };
  auto EXPP = [&]() {
    // exp in registers; pf built by packing (k-block0[r], k-block1[r]) pairs
    // -> key order [q4+0, 16+q4+0, q4+1, ...] == vtb's baked interleave.
    float p0[8], p1[8];
#pragma unroll
    for (int r = 0; r < 4; ++r) {
      p0[r]     = __expf(fmaf(s00[r], scale, -8.0f));
      p0[4 + r] = __expf(fmaf(s01[r], scale, -8.0f));
      p1[r]     = __expf(fmaf(s10[r], scale, -8.0f));
      p1[4 + r] = __expf(fmaf(s11[r], scale, -8.0f));
    }
#pragma unroll
    for (int r = 0; r < 8; ++r) { ls0 += p0[r]; ls1 += p1[r]; }
    union { uint4 u; bf16x8 v; } c0, c1;
    c0.u.x = pack2bf_ru(p0[0], p0[4]);
    c0.u.y = pack2bf_ru(p0[1], p0[5]);
    c0.u.z = pack2bf_ru(p0[2], p0[6]);
    c0.u.w = pack2bf_ru(p0[3], p0[7]);
    c1.u.x = pack2bf_ru(p1[0], p1[4]);
    c1.u.y = pack2bf_ru(p1[1], p1[5]);
    c1.u.z = pack2bf_ru(p1[2], p1[6]);
    c1.u.w = pack2bf_ru(p1[3], p1[7]);
    pf0 = c0.v;
    pf1 = c1.v;
  };

  // prologue: DMA K(0) -> Kl[0]
#pragma unroll
  for (int q = 0; q < 4; ++q)
    gld16(kbase + (size_t)kt0 * 8192 + sl + q * 512, &Kl[0][sl + q * 512]);

  // ---- iter 0 (peel: no PV yet) ----
  __syncthreads();  // drains K(0)
#pragma unroll
  for (int q = 0; q < 4; ++q) {
    gld16(vbase + (size_t)kt0 * 8192 + sl + q * 512, &Vt[0][sl + q * 512]);
    gld16(kbase + (size_t)(kt0 + 1) * 8192 + sl + q * 512, &Kl[1][sl + q * 512]);
  }
  QK(Kl[0]);
  EXPP();  // -> pf(0)

  // ---- main loop t = 1..31: {QK(t) ∥ PV(t-1)} ; exp(t) ----
#pragma unroll 1
  for (int t = 1; t < 32; ++t) {
    __syncthreads();  // ONLY barrier: drains K(t) + V(t-1) DMA, orders bufs
    {  // DMA V(t) -> Vt[t&1]  (Vt[t&1] last read by PV(t-2), done pre-barrier)
      const size_t vb = (size_t)(kt0 + t) * 8192;
#pragma unroll
      for (int q = 0; q < 4; ++q)
        gld16(vbase + vb + sl + q * 512, &Vt[t & 1][sl + q * 512]);
    }
    if (t < 31) {  // DMA K(t+1) -> Kl[(t+1)&1] (last read by QK(t-1))
      const size_t kbo = (size_t)(kt0 + t + 1) * 8192;
#pragma unroll
      for (int q = 0; q < 4; ++q)
        gld16(kbase + kbo + sl + q * 512, &Kl[(t + 1) & 1][sl + q * 512]);
    }
    QKPV(Kl[t & 1], Vt[(t - 1) & 1]);  // interleaved MFMA clusters
    EXPP();                            // VALU tail; -> pf(t)
  }
  // final PV(31): V(31) DMA'd at iter-31 top; drain it before reading.
  __syncthreads();
  PV(Vt[1]);

  // epilogue: write UNDIVIDED partial O and partial l (FULLY UNROLLED).
  // l: per-lane partial covers keys {quad*4+r} ∪ {16+quad*4+r}; reduce
  // across the 4 quads (lanes sharing lane&15) via xor 16, 32.
  float l0 = ls0 + __shfl_xor(ls0, 16);
  l0 += __shfl_xor(l0, 32);
  float l1 = ls1 + __shfl_xor(ls1, 16);
  l1 += __shfl_xor(l1, 32);
  const int lb = (h == 0 ? 0 : 32768) + b * 2048 + n0;
  if (quad == 0) {  // one lane per query
    lbuf[lb + col] = l0;
    lbuf[lb + 16 + col] = l1;
  }
  if (h == 0) {
#pragma unroll
    for (int ft = 0; ft < 16; ++ft) {
#pragma unroll
      for (int r = 0; r < 4; ++r) {
        const int n = n0 + quad * 4 + r;
        outA[(size_t)(b * 2048 + n) * 256 + ft * 16 + col] = O0[ft][r];
        outA[(size_t)(b * 2048 + n + 16) * 256 + ft * 16 + col] = O1[ft][r];
      }
    }
  } else {
#pragma unroll
    for (int ft = 0; ft < 16; ++ft) {
#pragma unroll
      for (int r = 0; r < 4; ++r) {
        const int n = n0 + quad * 4 + r;
        obB[(size_t)(b * 2048 + n) * 256 + ft * 16 + col] = f2bf(O0[ft][r]);
        obB[(size_t)(b * 2048 + n + 16) * 256 + ft * 16 + col] = f2bf(O1[ft][r]);
      }
    }
  }
}

// ---------------- kernel 3: combine K-split partials ----------------
__global__ __launch_bounds__(256) void k_reduce(
    float* __restrict__ out, const unsigned short* __restrict__ ob,
    const float* __restrict__ lbuf) {
  const size_t i4 = (size_t)blockIdx.x * 256 + threadIdx.x;  // 2M float4's
  const int bn = (int)(i4 >> 6);
  const float rl = 1.0f / (lbuf[bn] + lbuf[32768 + bn]);
  float4 o = ((const float4*)out)[i4];
  ushort4 b4 = ((const ushort4*)ob)[i4];
  o.x = (o.x + bf2f(b4.x)) * rl;
  o.y = (o.y + bf2f(b4.y)) * rl;
  o.z = (o.z + bf2f(b4.z)) * rl;
  o.w = (o.w + bf2f(b4.w)) * rl;
  ((float4*)out)[i4] = o;
}

// ---------------- launcher ----------------
extern "C" void kernel_launch(void* const* d_in, const int* in_sizes, int n_in,
                              void* d_out, int out_size, void* d_ws, size_t ws_size,
                              hipStream_t stream) {
  const float* x  = (const float*)d_in[0];
  const float* p  = (const float*)d_in[1];
  const float* Wq = (const float*)d_in[2];
  const float* bq = (const float*)d_in[3];
  const float* Wk = (const float*)d_in[4];
  const float* bk = (const float*)d_in[5];
  const float* Wv = (const float*)d_in[6];
  const float* bv = (const float*)d_in[7];
  const float* W1 = (const float*)d_in[8];
  const float* b1 = (const float*)d_in[9];
  const float* W2 = (const float*)d_in[10];
  const float* b2 = (const float*)d_in[11];
  float* out = (float*)d_out;

  char* ws = (char*)d_ws;
  unsigned short* W2b = (unsigned short*)(ws + 0);
  unsigned short* Wqb = (unsigned short*)(ws + 131072);
  unsigned short* Wkb = (unsigned short*)(ws + 262144);
  unsigned short* Wvb = (unsigned short*)(ws + 393216);
  unsigned short* obB = (unsigned short*)(ws + 524288);            // 16 MB
  unsigned short* qb  = (unsigned short*)(ws + 524288 + 16777216);
  unsigned short* kb  = (unsigned short*)(ws + 524288 + 2 * 16777216);
  unsigned short* vtb = (unsigned short*)(ws + 524288 + 3 * 16777216);
  float* lbuf = (float*)(ws + 524288 + 4 * 16777216);              // 256 KB
  // total ws use: 524288 + 4*16777216 + 262144 = 67,895,296 bytes

  k_wcvt<<<256, 256, 0, stream>>>(Wq, Wk, Wv, W2, Wqb, Wkb, Wvb, W2b);
  k_posqkv<<<512, 256, 0, stream>>>(x, p, W1, b1, W2b, b2,
                                    Wqb, bq, Wkb, bk, Wvb, bv, qb, kb, vtb);
  k_attn<<<512, 256, 0, stream>>>(qb, kb, vtb, out, obB, lbuf);
  k_reduce<<<8192, 256, 0, stream>>>(out, obB, lbuf);
}